// Round 6
// baseline (1054.340 us; speedup 1.0000x reference)
//
#include <hip/hip_runtime.h>
#include <hip/hip_bf16.h>

typedef unsigned short u16;
typedef unsigned int u32;
typedef __attribute__((ext_vector_type(8))) short bf16x8;
typedef __attribute__((ext_vector_type(4))) float f32x4;
typedef __attribute__((ext_vector_type(4))) float float4v;

__device__ __forceinline__ float bf2f(u16 v) {
  union { u32 u; float f; } x; x.u = ((u32)v) << 16; return x.f;
}
__device__ __forceinline__ u16 f2bf(float f) {
  union { u32 u; float f; } x; x.f = f;
  return (u16)((x.u + 0x7fffu + ((x.u >> 16) & 1u)) >> 16);
}

__device__ __forceinline__ void gload16(const void* g, void* l) {
  __builtin_amdgcn_global_load_lds(
      (const __attribute__((address_space(1))) u32*)g,
      (__attribute__((address_space(3))) u32*)l, 16, 0, 0);
}

#define MFMA16(a, bfr, cacc) __builtin_amdgcn_mfma_f32_16x16x32_bf16((a), (bfr), (cacc), 0, 0, 0)

// ---------------- prep kernels ----------------

__global__ void transpose_kernel(const float* __restrict__ in, u16* __restrict__ out,
                                 int R, int C) {
  int t = blockIdx.x * blockDim.x + threadIdx.x;
  if (t >= R * C) return;
  int c = t / R, r = t % R;
  out[t] = f2bf(in[r * C + c]);
}

__global__ void bias_tab_kernel(const float* __restrict__ w1, const float* __restrict__ w2,
                                float* __restrict__ tab) {
  int t = blockIdx.x * blockDim.x + threadIdx.x;
  if (t >= 225 * 16) return;
  int r = t >> 4, h = t & 15;
  int i = r / 15, j = r % 15;
  float gi = (float)(i - 7) * (8.0f / 7.0f);
  float gj = (float)(j - 7) * (8.0f / 7.0f);
  float si = (gi > 0.f) ? 1.f : ((gi < 0.f) ? -1.f : 0.f);
  float sj = (gj > 0.f) ? 1.f : ((gj < 0.f) ? -1.f : 0.f);
  float t0 = si * log2f(fabsf(gi) + 1.0f) * (1.0f / 3.0f);
  float t1 = sj * log2f(fabsf(gj) + 1.0f) * (1.0f / 3.0f);
  float acc = 0.f;
  for (int k = 0; k < 512; ++k) {
    float a = t0 * w1[k] + t1 * w1[512 + k];
    float hs = a * fminf(fmaxf(a + 3.f, 0.f), 6.f) * (1.f / 6.f);
    acc += hs * w2[k * 16 + h];
  }
  tab[t] = acc;
}

__global__ void bias16_kernel(const float* __restrict__ tab, float* __restrict__ b16) {
  int t = blockIdx.x * blockDim.x + threadIdx.x;
  if (t >= 16 * 64 * 64) return;
  int h = t >> 12, nm = t & 4095, n = nm >> 6, m = nm & 63;
  int idx = ((n >> 3) - (m >> 3) + 7) * 15 + ((n & 7) - (m & 7) + 7);
  float b = tab[idx * 16 + h];
  b16[t] = 16.0f / (1.0f + expf(-b));
}

// ---------------- m97-style bf16 GEMM: C[M,N] = A[M,K] * Bt[N,K]^T ----------------
template <bool F32OUT>
__global__ __launch_bounds__(256) void gemm_bt(const u16* __restrict__ A,
                                               const u16* __restrict__ Bt,
                                               void* __restrict__ Cout,
                                               int M, int N, int K) {
  __shared__ u16 lA[128 * 64];
  __shared__ u16 lB[128 * 64];
  const int tid = threadIdx.x;
  const int w = tid >> 6, l = tid & 63;
  const int lg = l >> 4, li = l & 15;
  const int nbn = N >> 7;
  const int nwg = gridDim.x;
  int bidx = blockIdx.x;
  int q = nwg >> 3, r = nwg & 7;
  int xcd = bidx & 7, pos = bidx >> 3;
  int swz = (xcd < r ? xcd * (q + 1) : r * (q + 1) + (xcd - r) * q) + pos;
  int bm = swz / nbn, bn = swz % nbn;
  const int wr = w >> 1, wc = w & 1;

  f32x4 acc[4][4];
#pragma unroll
  for (int i = 0; i < 4; i++)
#pragma unroll
    for (int j = 0; j < 4; j++) acc[i][j] = (f32x4){0.f, 0.f, 0.f, 0.f};

  const u16* Abase = A + (size_t)(bm * 128) * K;
  const u16* Bbase = Bt + (size_t)(bn * 128) * K;

  for (int k0 = 0; k0 < K; k0 += 64) {
#pragma unroll
    for (int i = 0; i < 4; ++i) {
      int c = w * 256 + i * 64 + l;
      int row = c >> 3, kc = c & 7;
      gload16(Abase + (size_t)row * K + k0 + kc * 8, (u16*)lA + c * 8);
      gload16(Bbase + (size_t)row * K + k0 + kc * 8, (u16*)lB + c * 8);
    }
    __syncthreads();
#pragma unroll
    for (int kk = 0; kk < 2; ++kk) {
      bf16x8 af[4], bfr[4];
#pragma unroll
      for (int t = 0; t < 4; ++t) {
        int row = wr * 64 + t * 16 + li;
        af[t] = *(const bf16x8*)&lA[row * 64 + kk * 32 + lg * 8];
        int col = wc * 64 + t * 16 + li;
        bfr[t] = *(const bf16x8*)&lB[col * 64 + kk * 32 + lg * 8];
      }
#pragma unroll
      for (int tm = 0; tm < 4; ++tm)
#pragma unroll
        for (int tn = 0; tn < 4; ++tn)
          acc[tm][tn] = MFMA16(af[tm], bfr[tn], acc[tm][tn]);
    }
    __syncthreads();
  }
  int r0 = bm * 128 + wr * 64 + lg * 4;
  int c0 = bn * 128 + wc * 64 + li;
#pragma unroll
  for (int tm = 0; tm < 4; ++tm)
#pragma unroll
    for (int tn = 0; tn < 4; ++tn)
#pragma unroll
      for (int j = 0; j < 4; ++j) {
        size_t off = (size_t)(r0 + tm * 16 + j) * N + c0 + tn * 16;
        if (F32OUT)
          ((float*)Cout)[off] = acc[tm][tn][j];
        else
          ((u16*)Cout)[off] = f2bf(acc[tm][tn][j]);
      }
}

// ---------------- fused: x->qkv GEMM -> cosine attn -> head-softmax -> PV ----------
// 1 block = 1 window, 16 waves = 16 heads.
// Register plan (peak ~95-100/thread):
//   P1: qa+ka (64) -> reduce norms, scale IN PLACE (no rqs/rks arrays) -> bounce
//   P2: va (32) -> dumped to LDS V-slab as bf16 -> freed
//   P3: qf+kf (32) + oacc (32) + softmax vals (16); V read from LDS
// LDS 136,192 B: phases 0-2: xl 64K + bb 64K; phase 3: S 66.5K + V 69.6K; P4: ob 132K
__global__ __launch_bounds__(1024, 4) void fused_attn(const float* __restrict__ x,
                                                      const float* __restrict__ mask,
                                                      const u16* __restrict__ wqkvT,
                                                      const float* __restrict__ bias16,
                                                      const float* __restrict__ lscale,
                                                      u16* __restrict__ aout) {
  __shared__ float S[34048];  // 136,192 B region, reused across phases
  u16* xl = (u16*)S;          // [64 rows][64 chunks16B] bf16, XOR-swizzled (64 KB)
  u16* bb = xl + 32768;       // q/k bounce: [16h][64n][32d] bf16, swizzled (64 KB)
  u16* vl = xl + 33280;       // V slab: [16h][64m][34] bf16 (byte 66,560..136,192)
  float* ob = S;              // phase 4: [64][516] f32

  const int tid = threadIdx.x;
  const int h = tid >> 6, l = tid & 63;
  const int lg = l >> 4, li = l & 15;
  const int b = blockIdx.x, wm = b & 63;
  const float* xg = x + (size_t)b * 64 * 512;

  // ---- phase 0: stage x fp32 -> bf16 LDS (16B-chunk index XOR n&7) ----
  {
    int n = tid >> 4, seg = tid & 15;
    const float4v* src = (const float4v*)(xg + n * 512 + seg * 32);
#pragma unroll
    for (int i = 0; i < 4; ++i) {
      float4v a = src[2 * i], c = src[2 * i + 1];
      union { bf16x8 v; u16 s[8]; } o;
      o.s[0] = f2bf(a[0]); o.s[1] = f2bf(a[1]); o.s[2] = f2bf(a[2]); o.s[3] = f2bf(a[3]);
      o.s[4] = f2bf(c[0]); o.s[5] = f2bf(c[1]); o.s[6] = f2bf(c[2]); o.s[7] = f2bf(c[3]);
      *(bf16x8*)(xl + ((n * 64 + ((seg * 4 + i) ^ (n & 7))) << 3)) = o.v;
    }
  }
  float sc = __expf(fminf(lscale[h], 4.6051702f));  // exp(min(ls, ln 100))
  __syncthreads();

  bf16x8 qf[4], kf[4];

  // ---- phase 1: q,k GEMM for head h; norms folded in place; bounce to frags ----
  {
    f32x4 qa[4][2], ka[4][2];
#pragma unroll
    for (int rt = 0; rt < 4; ++rt)
#pragma unroll
      for (int dt = 0; dt < 2; ++dt) {
        qa[rt][dt] = (f32x4){0.f, 0.f, 0.f, 0.f};
        ka[rt][dt] = (f32x4){0.f, 0.f, 0.f, 0.f};
      }
    const u16* bqp = wqkvT + (size_t)(h * 32) * 512;
    const u16* bkp = wqkvT + (size_t)(512 + h * 32) * 512;
#pragma unroll
    for (int kk = 0; kk < 16; ++kk) {
      bf16x8 ax[4];
#pragma unroll
      for (int rt = 0; rt < 4; ++rt) {
        int n = rt * 16 + li;
        ax[rt] = *(const bf16x8*)(xl + ((n * 64 + ((kk * 4 + lg) ^ (n & 7))) << 3));
      }
#pragma unroll
      for (int dt = 0; dt < 2; ++dt) {
        int coff = (dt * 16 + li) * 512 + kk * 32 + lg * 8;
        bf16x8 fq = *(const bf16x8*)(bqp + coff);
        bf16x8 fk = *(const bf16x8*)(bkp + coff);
#pragma unroll
        for (int rt = 0; rt < 4; ++rt) {
          qa[rt][dt] = MFMA16(ax[rt], fq, qa[rt][dt]);
          ka[rt][dt] = MFMA16(ax[rt], fk, ka[rt][dt]);
        }
      }
    }
    // norms: reduce over d (li lanes), scale accs in place (no persistent arrays)
#pragma unroll
    for (int rt = 0; rt < 4; ++rt) {
      f32x4 q2, k2;
#pragma unroll
      for (int j = 0; j < 4; ++j) {
        q2[j] = qa[rt][0][j] * qa[rt][0][j] + qa[rt][1][j] * qa[rt][1][j];
        k2[j] = ka[rt][0][j] * ka[rt][0][j] + ka[rt][1][j] * ka[rt][1][j];
      }
#pragma unroll
      for (int s = 1; s <= 8; s <<= 1)
#pragma unroll
        for (int j = 0; j < 4; ++j) {
          q2[j] += __shfl_xor(q2[j], s);
          k2[j] += __shfl_xor(k2[j], s);
        }
#pragma unroll
      for (int j = 0; j < 4; ++j) {
        float rq = sc / fmaxf(sqrtf(q2[j]), 1e-12f);
        float rk = 1.0f / fmaxf(sqrtf(k2[j]), 1e-12f);
#pragma unroll
        for (int dt = 0; dt < 2; ++dt) {
          qa[rt][dt][j] *= rq;
          ka[rt][dt][j] *= rk;
        }
      }
    }
    // bounce q through LDS (frees qa), then k
#pragma unroll
    for (int rt = 0; rt < 4; ++rt)
#pragma unroll
      for (int dt = 0; dt < 2; ++dt)
#pragma unroll
        for (int j = 0; j < 4; ++j) {
          int n = rt * 16 + lg * 4 + j;
          int d = dt * 16 + li;
          int s = (n ^ (n >> 2)) & 3;
          bb[h * 2048 + n * 32 + (((d >> 3) ^ s) << 3) + (d & 7)] = f2bf(qa[rt][dt][j]);
        }
    __syncthreads();
#pragma unroll
    for (int t = 0; t < 4; ++t) {
      int n = t * 16 + li;
      int s = (n ^ (n >> 2)) & 3;
      qf[t] = *(const bf16x8*)(bb + h * 2048 + n * 32 + ((lg ^ s) << 3));
    }
    __syncthreads();
#pragma unroll
    for (int rt = 0; rt < 4; ++rt)
#pragma unroll
      for (int dt = 0; dt < 2; ++dt)
#pragma unroll
        for (int j = 0; j < 4; ++j) {
          int n = rt * 16 + lg * 4 + j;
          int d = dt * 16 + li;
          int s = (n ^ (n >> 2)) & 3;
          bb[h * 2048 + n * 32 + (((d >> 3) ^ s) << 3) + (d & 7)] = f2bf(ka[rt][dt][j]);
        }
    __syncthreads();
#pragma unroll
    for (int t = 0; t < 4; ++t) {
      int n = t * 16 + li;
      int s = (n ^ (n >> 2)) & 3;
      kf[t] = *(const bf16x8*)(bb + h * 2048 + n * 32 + ((lg ^ s) << 3));
    }
  }
  __syncthreads();  // bb fully read; V slab (overlapping) may now be written

  // ---- phase 2: V GEMM (x still in LDS); dump accs to V slab as bf16 ----
  {
    f32x4 va[4][2];
#pragma unroll
    for (int rt = 0; rt < 4; ++rt)
#pragma unroll
      for (int dt = 0; dt < 2; ++dt) va[rt][dt] = (f32x4){0.f, 0.f, 0.f, 0.f};
    const u16* bvp = wqkvT + (size_t)(1024 + h * 32) * 512;
#pragma unroll
    for (int kk = 0; kk < 16; ++kk) {
      bf16x8 ax[4];
#pragma unroll
      for (int rt = 0; rt < 4; ++rt) {
        int n = rt * 16 + li;
        ax[rt] = *(const bf16x8*)(xl + ((n * 64 + ((kk * 4 + lg) ^ (n & 7))) << 3));
      }
#pragma unroll
      for (int dt = 0; dt < 2; ++dt) {
        bf16x8 fv = *(const bf16x8*)(bvp + (dt * 16 + li) * 512 + kk * 32 + lg * 8);
#pragma unroll
        for (int rt = 0; rt < 4; ++rt) va[rt][dt] = MFMA16(ax[rt], fv, va[rt][dt]);
      }
    }
    // write V slab [h][m][34-padded d]; own-head only (no cross-wave hazard)
    u16* vh = vl + h * 2176;
#pragma unroll
    for (int rt = 0; rt < 4; ++rt)
#pragma unroll
      for (int dt = 0; dt < 2; ++dt)
#pragma unroll
        for (int j = 0; j < 4; ++j) {
          int m = rt * 16 + lg * 4 + j;
          vh[m * 34 + dt * 16 + li] = f2bf(va[rt][dt][j]);
        }
  }
  __syncthreads();  // all xl reads done; S region (overlapping xl) live next

  const float* bias_h = bias16 + h * 4096;
  const float* mask_w = mask + wm * 4096;
  const u16* vh = vl + h * 2176;
  f32x4 oacc[4][2];
#pragma unroll
  for (int i = 0; i < 4; i++) {
    oacc[i][0] = (f32x4){0.f, 0.f, 0.f, 0.f};
    oacc[i][1] = (f32x4){0.f, 0.f, 0.f, 0.f};
  }

  // ---- phase 3: four 16-key chunks: QK^T -> +bias+mask -> head-softmax -> PV ----
#pragma unroll
  for (int c = 0; c < 4; ++c) {
#pragma unroll
    for (int tn = 0; tn < 4; ++tn) {
      f32x4 z = {0.f, 0.f, 0.f, 0.f};
      f32x4 s = MFMA16(qf[tn], kf[c], z);
      int mg = c * 16 + li;
#pragma unroll
      for (int j = 0; j < 4; ++j) {
        int n = tn * 16 + lg * 4 + j;
        S[h * 1040 + li * 65 + n] = s[j] + bias_h[n * 64 + mg] + mask_w[n * 64 + mg];
      }
    }
    __syncthreads();
    // softmax over 16 heads per (m,n): 1024 pairs / 1024 threads
    {
      int base = (tid >> 6) * 65 + (tid & 63);
      float vals[16];
      float mx = -3.0e38f;
#pragma unroll
      for (int hh = 0; hh < 16; ++hh) {
        vals[hh] = S[hh * 1040 + base];
        mx = fmaxf(mx, vals[hh]);
      }
      float sum = 0.f;
#pragma unroll
      for (int hh = 0; hh < 16; ++hh) {
        float e = __expf(vals[hh] - mx);
        vals[hh] = e;
        sum += e;
      }
      float inv = 1.0f / sum;
#pragma unroll
      for (int hh = 0; hh < 16; ++hh) S[hh * 1040 + base] = vals[hh] * inv;
    }
    __syncthreads();
    // PV: K=32 MFMA with upper 16 k zero-padded (lg>=2 lanes supply zeros)
#pragma unroll
    for (int td = 0; td < 2; ++td) {
      bf16x8 vf;
#pragma unroll
      for (int e = 0; e < 8; ++e)
        vf[e] = (lg < 2) ? (short)vh[(c * 16 + lg * 8 + e) * 34 + td * 16 + li]
                         : (short)0;
#pragma unroll
      for (int tn = 0; tn < 4; ++tn) {
        bf16x8 pf;
#pragma unroll
        for (int e = 0; e < 8; ++e)
          pf[e] = (lg < 2) ? (short)f2bf(S[h * 1040 + (lg * 8 + e) * 65 + tn * 16 + li])
                           : (short)0;
        oacc[tn][td] = MFMA16(pf, vf, oacc[tn][td]);
      }
    }
    __syncthreads();  // S reused by next chunk (or ob)
  }

  // ---- phase 4: coalesced output via LDS bounce ----
#pragma unroll
  for (int tn = 0; tn < 4; ++tn)
#pragma unroll
    for (int td = 0; td < 2; ++td)
#pragma unroll
      for (int j = 0; j < 4; ++j) {
        int n = tn * 16 + lg * 4 + j;
        ob[n * 516 + h * 32 + td * 16 + li] = oacc[tn][td][j];
      }
  __syncthreads();
  {
    int n = tid >> 4, seg = tid & 15;
    u16* dst = aout + ((size_t)b * 64 + n) * 512 + seg * 32;
    const float* srcr = ob + n * 516 + seg * 32;
#pragma unroll
    for (int i = 0; i < 4; ++i) {
      union { bf16x8 v; u16 s[8]; } o;
#pragma unroll
      for (int e = 0; e < 8; ++e) o.s[e] = f2bf(srcr[i * 8 + e]);
      *(bf16x8*)(dst + i * 8) = o.v;
    }
  }
}

extern "C" void kernel_launch(void* const* d_in, const int* in_sizes, int n_in,
                              void* d_out, int out_size, void* d_ws, size_t ws_size,
                              hipStream_t stream) {
  const float* x = (const float*)d_in[0];
  const float* mask = (const float*)d_in[1];
  const float* w_qkv = (const float*)d_in[2];
  const float* w_out = (const float*)d_in[3];
  const float* cpb_w1 = (const float*)d_in[4];
  const float* cpb_w2 = (const float*)d_in[5];
  const float* lscale = (const float*)d_in[6];
  float* out = (float*)d_out;

  char* ws = (char*)d_ws;
  u16* wqkvT = (u16*)ws;                    // 1,572,864 B
  u16* woutT = (u16*)(ws + 1572864ull);     // 524,288 B
  float* btab = (float*)(ws + 2097152ull);  // 16,384 B
  float* b16 = (float*)(ws + 2113536ull);   // 262,144 B
  u16* attn_out = (u16*)(ws + 2375680ull);  // 134,217,728 B

  transpose_kernel<<<(512 * 1536 + 255) / 256, 256, 0, stream>>>(w_qkv, wqkvT, 512, 1536);
  transpose_kernel<<<(512 * 512 + 255) / 256, 256, 0, stream>>>(w_out, woutT, 512, 512);
  bias_tab_kernel<<<(225 * 16 + 255) / 256, 256, 0, stream>>>(cpb_w1, cpb_w2, btab);
  bias16_kernel<<<(16 * 64 * 64 + 255) / 256, 256, 0, stream>>>(btab, b16);

  // fused x->qkv->attention, one block per window
  fused_attn<<<2048, 1024, 0, stream>>>(x, mask, wqkvT, b16, lscale, attn_out);

  // out = attn_out @ w_out  (M=131072, N=512, K=512), fp32 stores
  gemm_bt<true><<<4096, 256, 0, stream>>>(attn_out, woutT, out, 131072, 512, 512);
}

// Round 7
// 942.610 us; speedup vs baseline: 1.1185x; 1.1185x over previous
//
#include <hip/hip_runtime.h>
#include <hip/hip_bf16.h>

typedef unsigned short u16;
typedef unsigned int u32;
typedef __attribute__((ext_vector_type(8))) short bf16x8;
typedef __attribute__((ext_vector_type(4))) float f32x4;
typedef __attribute__((ext_vector_type(4))) float float4v;

__device__ __forceinline__ float bf2f(u16 v) {
  union { u32 u; float f; } x; x.u = ((u32)v) << 16; return x.f;
}
__device__ __forceinline__ u16 f2bf(float f) {
  union { u32 u; float f; } x; x.f = f;
  return (u16)((x.u + 0x7fffu + ((x.u >> 16) & 1u)) >> 16);
}

__device__ __forceinline__ void gload16(const void* g, void* l) {
  __builtin_amdgcn_global_load_lds(
      (const __attribute__((address_space(1))) u32*)g,
      (__attribute__((address_space(3))) u32*)l, 16, 0, 0);
}

#define MFMA16(a, bfr, cacc) __builtin_amdgcn_mfma_f32_16x16x32_bf16((a), (bfr), (cacc), 0, 0, 0)

// ---------------- prep kernels ----------------

__global__ void transpose_kernel(const float* __restrict__ in, u16* __restrict__ out,
                                 int R, int C) {
  int t = blockIdx.x * blockDim.x + threadIdx.x;
  if (t >= R * C) return;
  int c = t / R, r = t % R;
  out[t] = f2bf(in[r * C + c]);
}

// w_qkv -> per-(tensor,head) fragment-contiguous layout:
// bw2[whead*16384 + ((kk*2+dt)*4+lg)*128 + li*8 + e]
//   = bf16(w_qkv[(kk*32+lg*8+e)*1536 + s*512 + h*32 + dt*16 + li]), whead = s*16+h
__global__ void wqkv_swz_kernel(const float* __restrict__ w, u16* __restrict__ out) {
  int t = blockIdx.x * blockDim.x + threadIdx.x;
  if (t >= 48 * 16384) return;
  int whead = t >> 14;
  int rest = t & 16383;
  int chunk = rest >> 7;          // 0..127
  int kk = chunk >> 3, dt = (chunk >> 2) & 1, lg = chunk & 3;
  int li = (rest >> 3) & 15, e = rest & 7;
  int s = whead >> 4, h = whead & 15;
  out[t] = f2bf(w[(size_t)(kk * 32 + lg * 8 + e) * 1536 + s * 512 + h * 32 + dt * 16 + li]);
}

__global__ void bias_tab_kernel(const float* __restrict__ w1, const float* __restrict__ w2,
                                float* __restrict__ tab) {
  int t = blockIdx.x * blockDim.x + threadIdx.x;
  if (t >= 225 * 16) return;
  int r = t >> 4, h = t & 15;
  int i = r / 15, j = r % 15;
  float gi = (float)(i - 7) * (8.0f / 7.0f);
  float gj = (float)(j - 7) * (8.0f / 7.0f);
  float si = (gi > 0.f) ? 1.f : ((gi < 0.f) ? -1.f : 0.f);
  float sj = (gj > 0.f) ? 1.f : ((gj < 0.f) ? -1.f : 0.f);
  float t0 = si * log2f(fabsf(gi) + 1.0f) * (1.0f / 3.0f);
  float t1 = sj * log2f(fabsf(gj) + 1.0f) * (1.0f / 3.0f);
  float acc = 0.f;
  for (int k = 0; k < 512; ++k) {
    float a = t0 * w1[k] + t1 * w1[512 + k];
    float hs = a * fminf(fmaxf(a + 3.f, 0.f), 6.f) * (1.f / 6.f);
    acc += hs * w2[k * 16 + h];
  }
  tab[t] = acc;
}

__global__ void bias16_kernel(const float* __restrict__ tab, float* __restrict__ b16) {
  int t = blockIdx.x * blockDim.x + threadIdx.x;
  if (t >= 16 * 64 * 64) return;
  int h = t >> 12, nm = t & 4095, n = nm >> 6, m = nm & 63;
  int idx = ((n >> 3) - (m >> 3) + 7) * 15 + ((n & 7) - (m & 7) + 7);
  float b = tab[idx * 16 + h];
  b16[t] = 16.0f / (1.0f + expf(-b));
}

// ---------------- m97-style bf16 GEMM: C[M,N] = A[M,K] * Bt[N,K]^T ----------------
template <bool F32OUT>
__global__ __launch_bounds__(256) void gemm_bt(const u16* __restrict__ A,
                                               const u16* __restrict__ Bt,
                                               void* __restrict__ Cout,
                                               int M, int N, int K) {
  __shared__ u16 lA[128 * 64];
  __shared__ u16 lB[128 * 64];
  const int tid = threadIdx.x;
  const int w = tid >> 6, l = tid & 63;
  const int lg = l >> 4, li = l & 15;
  const int nbn = N >> 7;
  const int nwg = gridDim.x;
  int bidx = blockIdx.x;
  int q = nwg >> 3, r = nwg & 7;
  int xcd = bidx & 7, pos = bidx >> 3;
  int swz = (xcd < r ? xcd * (q + 1) : r * (q + 1) + (xcd - r) * q) + pos;
  int bm = swz / nbn, bn = swz % nbn;
  const int wr = w >> 1, wc = w & 1;

  f32x4 acc[4][4];
#pragma unroll
  for (int i = 0; i < 4; i++)
#pragma unroll
    for (int j = 0; j < 4; j++) acc[i][j] = (f32x4){0.f, 0.f, 0.f, 0.f};

  const u16* Abase = A + (size_t)(bm * 128) * K;
  const u16* Bbase = Bt + (size_t)(bn * 128) * K;

  for (int k0 = 0; k0 < K; k0 += 64) {
#pragma unroll
    for (int i = 0; i < 4; ++i) {
      int c = w * 256 + i * 64 + l;
      int row = c >> 3, kc = c & 7;
      gload16(Abase + (size_t)row * K + k0 + kc * 8, (u16*)lA + c * 8);
      gload16(Bbase + (size_t)row * K + k0 + kc * 8, (u16*)lB + c * 8);
    }
    __syncthreads();
#pragma unroll
    for (int kk = 0; kk < 2; ++kk) {
      bf16x8 af[4], bfr[4];
#pragma unroll
      for (int t = 0; t < 4; ++t) {
        int row = wr * 64 + t * 16 + li;
        af[t] = *(const bf16x8*)&lA[row * 64 + kk * 32 + lg * 8];
        int col = wc * 64 + t * 16 + li;
        bfr[t] = *(const bf16x8*)&lB[col * 64 + kk * 32 + lg * 8];
      }
#pragma unroll
      for (int tm = 0; tm < 4; ++tm)
#pragma unroll
        for (int tn = 0; tn < 4; ++tn)
          acc[tm][tn] = MFMA16(af[tm], bfr[tn], acc[tm][tn]);
    }
    __syncthreads();
  }
  int r0 = bm * 128 + wr * 64 + lg * 4;
  int c0 = bn * 128 + wc * 64 + li;
#pragma unroll
  for (int tm = 0; tm < 4; ++tm)
#pragma unroll
    for (int tn = 0; tn < 4; ++tn)
#pragma unroll
      for (int j = 0; j < 4; ++j) {
        size_t off = (size_t)(r0 + tm * 16 + j) * N + c0 + tn * 16;
        if (F32OUT)
          ((float*)Cout)[off] = acc[tm][tn][j];
        else
          ((u16*)Cout)[off] = f2bf(acc[tm][tn][j]);
      }
}

// ---------------- fused: x->qkv GEMM -> cosine attn -> head-softmax -> PV ----------
// 1 block = 1 window, 16 waves = 16 heads. waves_per_eu(4,4): allow 128 VGPRs.
// Softmax is 3 in-place LDS passes (no vals[16] array -> no spill candidate).
// P stored once as bf16 in the low half of its f32 slot; PV reads u16 directly.
__global__ __launch_bounds__(1024)
__attribute__((amdgpu_waves_per_eu(4, 4))) void fused_attn(
    const float* __restrict__ x, const float* __restrict__ mask,
    const u16* __restrict__ wqkv2, const float* __restrict__ bias16,
    const float* __restrict__ lscale, u16* __restrict__ aout) {
  __shared__ float S[33280];  // 133,120 B region, reused across phases
  u16* xl = (u16*)S;          // [64 rows][64 chunks16B] bf16, XOR-swizzled (64 KB)
  u16* bb = xl + 32768;       // q/k bounce: [16h][64n][32d] bf16, swizzled (64 KB)
  float* ob = S;              // phase 4: [64][516] f32
  u16* P16 = (u16*)S;         // phase 3: bf16 P in-place (low half of f32 slots)

  const int tid = threadIdx.x;
  const int h = tid >> 6, l = tid & 63;
  const int lg = l >> 4, li = l & 15;
  const int b = blockIdx.x, wm = b & 63;
  const float* xg = x + (size_t)b * 64 * 512;

  // ---- phase 0: stage x fp32 -> bf16 LDS (16B-chunk index XOR n&7) ----
  {
    int n = tid >> 4, seg = tid & 15;
    const float4v* src = (const float4v*)(xg + n * 512 + seg * 32);
#pragma unroll
    for (int i = 0; i < 4; ++i) {
      float4v a = src[2 * i], c = src[2 * i + 1];
      union { bf16x8 v; u16 s[8]; } o;
      o.s[0] = f2bf(a[0]); o.s[1] = f2bf(a[1]); o.s[2] = f2bf(a[2]); o.s[3] = f2bf(a[3]);
      o.s[4] = f2bf(c[0]); o.s[5] = f2bf(c[1]); o.s[6] = f2bf(c[2]); o.s[7] = f2bf(c[3]);
      *(bf16x8*)(xl + ((n * 64 + ((seg * 4 + i) ^ (n & 7))) << 3)) = o.v;
    }
  }
  float sc = __expf(fminf(lscale[h], 4.6051702f));  // exp(min(ls, ln 100))
  __syncthreads();

  bf16x8 qf[4], kf[4];

  // ---- phase 1: q,k GEMM; in-place norm fold; bounce to MFMA operand frags ----
  {
    f32x4 qa[4][2], ka[4][2];
#pragma unroll
    for (int rt = 0; rt < 4; ++rt)
#pragma unroll
      for (int dt = 0; dt < 2; ++dt) {
        qa[rt][dt] = (f32x4){0.f, 0.f, 0.f, 0.f};
        ka[rt][dt] = (f32x4){0.f, 0.f, 0.f, 0.f};
      }
    const u16* bq2 = wqkv2 + (size_t)h * 16384;
    const u16* bk2 = wqkv2 + (size_t)(16 + h) * 16384;
#pragma unroll
    for (int kk = 0; kk < 16; ++kk) {
      bf16x8 ax[4];
#pragma unroll
      for (int rt = 0; rt < 4; ++rt) {
        int n = rt * 16 + li;
        ax[rt] = *(const bf16x8*)(xl + ((n * 64 + ((kk * 4 + lg) ^ (n & 7))) << 3));
      }
#pragma unroll
      for (int dt = 0; dt < 2; ++dt) {
        int coff = (kk * 2 + dt) * 512 + lg * 128 + li * 8;  // coalesced frag layout
        bf16x8 fq = *(const bf16x8*)(bq2 + coff);
        bf16x8 fk = *(const bf16x8*)(bk2 + coff);
#pragma unroll
        for (int rt = 0; rt < 4; ++rt) {
          qa[rt][dt] = MFMA16(ax[rt], fq, qa[rt][dt]);
          ka[rt][dt] = MFMA16(ax[rt], fk, ka[rt][dt]);
        }
      }
    }
    // norms: reduce over d (li lanes), scale accs in place
#pragma unroll
    for (int rt = 0; rt < 4; ++rt) {
      f32x4 q2, k2;
#pragma unroll
      for (int j = 0; j < 4; ++j) {
        q2[j] = qa[rt][0][j] * qa[rt][0][j] + qa[rt][1][j] * qa[rt][1][j];
        k2[j] = ka[rt][0][j] * ka[rt][0][j] + ka[rt][1][j] * ka[rt][1][j];
      }
#pragma unroll
      for (int s = 1; s <= 8; s <<= 1)
#pragma unroll
        for (int j = 0; j < 4; ++j) {
          q2[j] += __shfl_xor(q2[j], s);
          k2[j] += __shfl_xor(k2[j], s);
        }
#pragma unroll
      for (int j = 0; j < 4; ++j) {
        float rq = sc / fmaxf(sqrtf(q2[j]), 1e-12f);
        float rk = 1.0f / fmaxf(sqrtf(k2[j]), 1e-12f);
#pragma unroll
        for (int dt = 0; dt < 2; ++dt) {
          qa[rt][dt][j] *= rq;
          ka[rt][dt][j] *= rk;
        }
      }
    }
    // bounce q through LDS (frees qa), then k
#pragma unroll
    for (int rt = 0; rt < 4; ++rt)
#pragma unroll
      for (int dt = 0; dt < 2; ++dt)
#pragma unroll
        for (int j = 0; j < 4; ++j) {
          int n = rt * 16 + lg * 4 + j;
          int d = dt * 16 + li;
          int s = (n ^ (n >> 2)) & 3;
          bb[h * 2048 + n * 32 + (((d >> 3) ^ s) << 3) + (d & 7)] = f2bf(qa[rt][dt][j]);
        }
    __syncthreads();
#pragma unroll
    for (int t = 0; t < 4; ++t) {
      int n = t * 16 + li;
      int s = (n ^ (n >> 2)) & 3;
      qf[t] = *(const bf16x8*)(bb + h * 2048 + n * 32 + ((lg ^ s) << 3));
    }
    __syncthreads();
#pragma unroll
    for (int rt = 0; rt < 4; ++rt)
#pragma unroll
      for (int dt = 0; dt < 2; ++dt)
#pragma unroll
        for (int j = 0; j < 4; ++j) {
          int n = rt * 16 + lg * 4 + j;
          int d = dt * 16 + li;
          int s = (n ^ (n >> 2)) & 3;
          bb[h * 2048 + n * 32 + (((d >> 3) ^ s) << 3) + (d & 7)] = f2bf(ka[rt][dt][j]);
        }
    __syncthreads();
#pragma unroll
    for (int t = 0; t < 4; ++t) {
      int n = t * 16 + li;
      int s = (n ^ (n >> 2)) & 3;
      kf[t] = *(const bf16x8*)(bb + h * 2048 + n * 32 + ((lg ^ s) << 3));
    }
  }

  // ---- phase 2: V GEMM (x still in LDS); va stays in accumulators ----
  f32x4 va[4][2];
#pragma unroll
  for (int rt = 0; rt < 4; ++rt)
#pragma unroll
    for (int dt = 0; dt < 2; ++dt) va[rt][dt] = (f32x4){0.f, 0.f, 0.f, 0.f};
  {
    const u16* bv2 = wqkv2 + (size_t)(32 + h) * 16384;
#pragma unroll
    for (int kk = 0; kk < 16; ++kk) {
      bf16x8 ax[4];
#pragma unroll
      for (int rt = 0; rt < 4; ++rt) {
        int n = rt * 16 + li;
        ax[rt] = *(const bf16x8*)(xl + ((n * 64 + ((kk * 4 + lg) ^ (n & 7))) << 3));
      }
#pragma unroll
      for (int dt = 0; dt < 2; ++dt) {
        bf16x8 fv = *(const bf16x8*)(bv2 + (kk * 2 + dt) * 512 + lg * 128 + li * 8);
#pragma unroll
        for (int rt = 0; rt < 4; ++rt) va[rt][dt] = MFMA16(ax[rt], fv, va[rt][dt]);
      }
    }
  }
  __syncthreads();  // x + bounce dead; S region live next

  const float* bias_h = bias16 + h * 4096;
  const float* mask_w = mask + wm * 4096;
  f32x4 oacc[4][2];
#pragma unroll
  for (int i = 0; i < 4; i++) {
    oacc[i][0] = (f32x4){0.f, 0.f, 0.f, 0.f};
    oacc[i][1] = (f32x4){0.f, 0.f, 0.f, 0.f};
  }

  // ---- phase 3: two 32-key chunks: QK^T -> +bias+mask -> head-softmax -> PV ----
#pragma unroll
  for (int c = 0; c < 2; ++c) {
#pragma unroll
    for (int tn = 0; tn < 4; ++tn)
#pragma unroll
      for (int t = 0; t < 2; ++t) {
        int mt = c * 2 + t;
        f32x4 z = {0.f, 0.f, 0.f, 0.f};
        f32x4 s = MFMA16(qf[tn], kf[mt], z);
        int mloc = t * 16 + li;
        int mg = c * 32 + mloc;
#pragma unroll
        for (int j = 0; j < 4; ++j) {
          int n = tn * 16 + lg * 4 + j;
          S[h * 2080 + mloc * 65 + n] = s[j] + bias_h[n * 64 + mg] + mask_w[n * 64 + mg];
        }
      }
    __syncthreads();
    // softmax over 16 heads per (m,n): 3 in-place passes, minimal live regs
#pragma unroll
    for (int pp = 0; pp < 2; ++pp) {
      int p = tid + pp * 1024;
      int base = (p >> 6) * 65 + (p & 63);
      float mx = -3.0e38f;
#pragma unroll
      for (int hh = 0; hh < 16; ++hh) mx = fmaxf(mx, S[hh * 2080 + base]);
      float sum = 0.f;
#pragma unroll
      for (int hh = 0; hh < 16; ++hh) {
        float e = __expf(S[hh * 2080 + base] - mx);
        S[hh * 2080 + base] = e;
        sum += e;
      }
      float inv = 1.0f / sum;
#pragma unroll
      for (int hh = 0; hh < 16; ++hh)
        P16[(hh * 2080 + base) * 2] = f2bf(S[hh * 2080 + base] * inv);
    }
    __syncthreads();
    // V frags from registers via shuffles (verified layout)
    bf16x8 vf[2];
#pragma unroll
    for (int td = 0; td < 2; ++td)
#pragma unroll
      for (int j = 0; j < 8; ++j) {
        int srcl = (((lg * 2 + (j >> 2)) & 3) << 4) + li;
        float a0 = __shfl(va[c * 2][td][j & 3], srcl);
        float a1 = __shfl(va[c * 2 + 1][td][j & 3], srcl);
        vf[td][j] = (short)f2bf(lg >= 2 ? a1 : a0);
      }
    // P frags read directly as bf16
#pragma unroll
    for (int tn = 0; tn < 4; ++tn) {
      bf16x8 pf;
#pragma unroll
      for (int e = 0; e < 8; ++e)
        pf[e] = (short)P16[(h * 2080 + (lg * 8 + e) * 65 + tn * 16 + li) * 2];
      oacc[tn][0] = MFMA16(pf, vf[0], oacc[tn][0]);
      oacc[tn][1] = MFMA16(pf, vf[1], oacc[tn][1]);
    }
    __syncthreads();  // S reused by next chunk (or ob)
  }

  // ---- phase 4: coalesced output via LDS bounce ----
#pragma unroll
  for (int tn = 0; tn < 4; ++tn)
#pragma unroll
    for (int td = 0; td < 2; ++td)
#pragma unroll
      for (int j = 0; j < 4; ++j) {
        int n = tn * 16 + lg * 4 + j;
        ob[n * 516 + h * 32 + td * 16 + li] = oacc[tn][td][j];
      }
  __syncthreads();
  {
    int n = tid >> 4, seg = tid & 15;
    u16* dst = aout + ((size_t)b * 64 + n) * 512 + seg * 32;
    const float* srcr = ob + n * 516 + seg * 32;
#pragma unroll
    for (int i = 0; i < 4; ++i) {
      union { bf16x8 v; u16 s[8]; } o;
#pragma unroll
      for (int e = 0; e < 8; ++e) o.s[e] = f2bf(srcr[i * 8 + e]);
      *(bf16x8*)(dst + i * 8) = o.v;
    }
  }
}

extern "C" void kernel_launch(void* const* d_in, const int* in_sizes, int n_in,
                              void* d_out, int out_size, void* d_ws, size_t ws_size,
                              hipStream_t stream) {
  const float* x = (const float*)d_in[0];
  const float* mask = (const float*)d_in[1];
  const float* w_qkv = (const float*)d_in[2];
  const float* w_out = (const float*)d_in[3];
  const float* cpb_w1 = (const float*)d_in[4];
  const float* cpb_w2 = (const float*)d_in[5];
  const float* lscale = (const float*)d_in[6];
  float* out = (float*)d_out;

  char* ws = (char*)d_ws;
  u16* wqkv2 = (u16*)ws;                    // 1,572,864 B (swizzled frag layout)
  u16* woutT = (u16*)(ws + 1572864ull);     // 524,288 B
  float* btab = (float*)(ws + 2097152ull);  // 16,384 B
  float* b16 = (float*)(ws + 2113536ull);   // 262,144 B
  u16* attn_out = (u16*)(ws + 2375680ull);  // 134,217,728 B

  wqkv_swz_kernel<<<(48 * 16384) / 256, 256, 0, stream>>>(w_qkv, wqkv2);
  transpose_kernel<<<(512 * 512 + 255) / 256, 256, 0, stream>>>(w_out, woutT, 512, 512);
  bias_tab_kernel<<<(225 * 16 + 255) / 256, 256, 0, stream>>>(cpb_w1, cpb_w2, btab);
  bias16_kernel<<<(16 * 64 * 64 + 255) / 256, 256, 0, stream>>>(btab, b16);

  // fused x->qkv->attention, one block per window
  fused_attn<<<2048, 1024, 0, stream>>>(x, mask, wqkv2, b16, lscale, attn_out);

  // out = attn_out @ w_out  (M=131072, N=512, K=512), fp32 stores
  gemm_bt<true><<<4096, 256, 0, stream>>>(attn_out, woutT, out, 131072, 512, 512);
}